// Round 3
// baseline (829.388 us; speedup 1.0000x reference)
//
#include <hip/hip_runtime.h>

#define NN 4096

// Scratch in the device image -- fully rewritten before every read on every
// call (stateless across calls), no dependence on ws_size.
__device__ float g_outf[NN*8];
__device__ float g_agg0[NN*8];
__device__ float g_agg1[NN*8];

__device__ __forceinline__ float lrelu(float x){ return x > 0.0f ? x : 0.01f * x; }

// Full 3-layer MLP (8->16->8->8), leaky_relu(0.01) after every layer.
__device__ void mlp3(const float* in,
                     const float* W1, const float* b1,
                     const float* W2, const float* b2,
                     const float* W3, const float* b3, float* out)
{
  float h1[16];
  #pragma unroll
  for (int m=0;m<16;m++){
    float s = b1[m];
    #pragma unroll
    for (int k=0;k<8;k++) s += in[k]*W1[k*16+m];
    h1[m] = lrelu(s);
  }
  float h2[8];
  #pragma unroll
  for (int m=0;m<8;m++){
    float s = b2[m];
    #pragma unroll
    for (int k=0;k<16;k++) s += h1[k]*W2[k*8+m];
    h2[m] = lrelu(s);
  }
  #pragma unroll
  for (int c=0;c<8;c++){
    float s = b3[c];
    #pragma unroll
    for (int k=0;k<8;k++) s += h2[k]*W3[k*8+c];
    out[c] = lrelu(s);
  }
}

// out0 = MLP_p(x); agg0 = MLP_a(out0). One thread per row.
__global__ __launch_bounds__(256) void init_kernel(
    const float* __restrict__ x,
    const float* pW1,const float* pb1,const float* pW2,const float* pb2,const float* pW3,const float* pb3,
    const float* aW1,const float* ab1,const float* aW2,const float* ab2,const float* aW3,const float* ab3)
{
  int i = blockIdx.x*256 + threadIdx.x;
  float in[8];
  #pragma unroll
  for (int k=0;k<8;k++) in[k] = x[i*8+k];
  float o[8];
  mlp3(in, pW1,pb1,pW2,pb2,pW3,pb3, o);
  #pragma unroll
  for (int c=0;c<8;c++) g_outf[i*8+c] = o[c];
  float a[8];
  mlp3(o, aW1,ab1,aW2,ab2,aW3,ab3, a);
  #pragma unroll
  for (int c=0;c<8;c++) g_agg0[i*8+c] = a[c];
}

// out[i] += A[i,:] @ aggin  (4 rows per wave, f32), then epilogue computes
// aggout = MLP_a(out_new) lane-parallel, or writes final f32 output at d=7.
__global__ __launch_bounds__(256,1) void agg_update(
    const float* __restrict__ A, int parity, float* __restrict__ finout,
    const float* __restrict__ aW1,const float* __restrict__ ab1,
    const float* __restrict__ aW2,const float* __restrict__ ab2,
    const float* __restrict__ aW3,const float* __restrict__ ab3)
{
  const float* aggin  = parity ? g_agg1 : g_agg0;
  float*       aggout = parity ? g_agg0 : g_agg1;

  const int lane = threadIdx.x & 63;
  const int wav  = threadIdx.x >> 6;
  const int i0   = (blockIdx.x*4 + wav) * 4;   // 4 rows per wave

  const float4* Ar0 = reinterpret_cast<const float4*>(A + (size_t)(i0+0)*NN) + lane;
  const float4* Ar1 = reinterpret_cast<const float4*>(A + (size_t)(i0+1)*NN) + lane;
  const float4* Ar2 = reinterpret_cast<const float4*>(A + (size_t)(i0+2)*NN) + lane;
  const float4* Ar3 = reinterpret_cast<const float4*>(A + (size_t)(i0+3)*NN) + lane;
  const float4* gp  = reinterpret_cast<const float4*>(aggin) + (size_t)lane*8;

  float acc[4][8];
  #pragma unroll
  for (int r=0;r<4;r++)
    #pragma unroll
    for (int c=0;c<8;c++) acc[r][c] = 0.0f;

  // lane l covers j = it*256 + 4*l .. +3; wave covers 256 j per iteration
  for (int it=0; it<16; ++it){
    float4 a0 = Ar0[it*64];
    float4 a1 = Ar1[it*64];
    float4 a2 = Ar2[it*64];
    float4 a3 = Ar3[it*64];
    float4 g[8];
    #pragma unroll
    for (int t=0;t<8;t++) g[t] = gp[it*512 + t];

    const float av[4][4] = {{a0.x,a0.y,a0.z,a0.w},
                            {a1.x,a1.y,a1.z,a1.w},
                            {a2.x,a2.y,a2.z,a2.w},
                            {a3.x,a3.y,a3.z,a3.w}};
    #pragma unroll
    for (int jj=0;jj<4;jj++){
      const float gl[8] = {g[2*jj].x, g[2*jj].y, g[2*jj].z, g[2*jj].w,
                           g[2*jj+1].x, g[2*jj+1].y, g[2*jj+1].z, g[2*jj+1].w};
      #pragma unroll
      for (int r=0;r<4;r++){
        const float a = av[r][jj];
        #pragma unroll
        for (int c=0;c<8;c++) acc[r][c] += a*gl[c];
      }
    }
  }

  // 64-lane butterfly reduce: afterwards every lane holds all 32 totals
  #pragma unroll
  for (int r=0;r<4;r++)
    #pragma unroll
    for (int c=0;c<8;c++){
      float v = acc[r][c];
      #pragma unroll
      for (int s=1;s<64;s<<=1) v += __shfl_xor(v, s, 64);
      acc[r][c] = v;
    }

  const int r = lane >> 4, m = lane & 15;
  float* po = g_outf + (size_t)i0*8;

  // new out row for this lane's MLP row (r = lane>>4)
  float rowv[8];
  #pragma unroll
  for (int k=0;k<8;k++) rowv[k] = po[r*8+k] + acc[r][k];

  // lanes 0..31 write the 32 updated values (loads above precede stores in wave order)
  if (lane < 32){
    float t = 0.0f;
    #pragma unroll
    for (int rr=0;rr<4;rr++)
      #pragma unroll
      for (int cc=0;cc<8;cc++)
        if (rr*8+cc == lane) t = acc[rr][cc];
    float sv = po[lane] + t;
    po[lane] = sv;
    if (finout) finout[(size_t)i0*8 + lane] = sv;
  }

  if (!finout){
    // lane-parallel MLP_a over 4 rows x 16 neurons
    float h1 = ab1[m];
    #pragma unroll
    for (int k=0;k<8;k++) h1 += rowv[k]*aW1[k*16+m];
    h1 = lrelu(h1);
    const int m8 = m & 7;
    float s2 = ab2[m8];
    #pragma unroll
    for (int k=0;k<16;k++) s2 += __shfl(h1, (lane & 48)+k, 64) * aW2[k*8+m8];
    float h2 = lrelu(s2);
    float s3 = ab3[m8];
    #pragma unroll
    for (int k=0;k<8;k++) s3 += __shfl(h2, (lane & 48)+k, 64) * aW3[k*8+m8];
    float av = lrelu(s3);
    if (m < 8) aggout[(size_t)(i0+r)*8 + m] = av;
  }
}

extern "C" void kernel_launch(void* const* d_in, const int* in_sizes, int n_in,
                              void* d_out, int out_size, void* d_ws, size_t ws_size,
                              hipStream_t stream)
{
  const float* x   = (const float*)d_in[0];
  const float* rem = (const float*)d_in[1];
  const float* pW1 = (const float*)d_in[2];
  const float* pb1 = (const float*)d_in[3];
  const float* pW2 = (const float*)d_in[4];
  const float* pb2 = (const float*)d_in[5];
  const float* pW3 = (const float*)d_in[6];
  const float* pb3 = (const float*)d_in[7];
  const float* aW1 = (const float*)d_in[8];
  const float* ab1 = (const float*)d_in[9];
  const float* aW2 = (const float*)d_in[10];
  const float* ab2 = (const float*)d_in[11];
  const float* aW3 = (const float*)d_in[12];
  const float* ab3 = (const float*)d_in[13];
  float* outf = (float*)d_out;

  init_kernel<<<16,256,0,stream>>>(x,pW1,pb1,pW2,pb2,pW3,pb3,
                                   aW1,ab1,aW2,ab2,aW3,ab3);
  for (int d=0; d<8; ++d){
    agg_update<<<256,256,0,stream>>>(rem + (size_t)d*NN*NN, (d&1),
                                     (d==7)? outf : (float*)nullptr,
                                     aW1,ab1,aW2,ab2,aW3,ab3);
  }
}